// Round 6
// baseline (5307.039 us; speedup 1.0000x reference)
//
#include <hip/hip_runtime.h>
#include <math.h>

// ---------------- problem constants ----------------
// B=64, P=196, H=E=A=512, V=10000, T=49, gates=2048
// gate col order n' = d*4+g  <->  W row j = g*512+d

// ---------------- ws layout (float element offsets) ----------------
#define WS_SORT   0             // int[64]
#define WS_DL     64            // int[64]
#define WS_NB     128           // int[64]: nb[0..48], [49]=R
#define WS_ROWOFF 192           // int[64]
#define WS_CAPS   256           // int[64*50]
#define WS_RMAP   3456          // int[3136]
#define WS_EROW   6592          // int[3136]
#define WS_CTXF   9728          // int[49*64] ctx-ready flags
#define WS_HF     12864         // int[49*16] h-ready flags (pad 800)
#define WS_BS     13664         // float[2048]: b_ih+b_hh in n' order
#define WS_C      15712         // float[64*512]
#define WS_XH     48480         // half[64][1024] = [ctx | h]  (ALL access via LLC-bypass atomics)
#define WS_WDT    81248         // half2[256][512]
#define WS_WGH    146784        // half[2048][1024] gates W, n' rows
#define WS_GEMB   1195360       // half[3136][2048]
#define WS_WSH    1195360       // overlay post-loop: half[10000*512]
#define WS_HALLH  4406624       // half[3136*512]
#define WS_ENCH   5209440       // half[12544*512]
// end = 8,420,704 floats = 33.7 MB

// ---------------- out layout (floats) ----------------
#define OUT_SCORES 0
#define OUT_CAPS   31360000
#define OUT_DL     31363200
#define OUT_W      31363264
#define OUT_SORT   31977920

typedef _Float16 f16x8 __attribute__((ext_vector_type(8)));
typedef _Float16 f16x4 __attribute__((ext_vector_type(4)));
typedef _Float16 f16x2 __attribute__((ext_vector_type(2)));
typedef float floatx4 __attribute__((ext_vector_type(4)));

__device__ __forceinline__ float sigm(float x) { return 1.f / (1.f + expf(-x)); }

__device__ __forceinline__ float wave_reduce_sum(float v) {
#pragma unroll
  for (int off = 32; off; off >>= 1) v += __shfl_down(v, off);
  return v;
}

__device__ __forceinline__ float dot2f(f16x2 a, f16x2 b, float c) {
#if defined(__has_builtin)
#if __has_builtin(__builtin_amdgcn_fdot2)
  return __builtin_amdgcn_fdot2(a, b, c, false);
#else
  return fmaf((float)a[0], (float)b[0], fmaf((float)a[1], (float)b[1], c));
#endif
#else
  return fmaf((float)a[0], (float)b[0], fmaf((float)a[1], (float)b[1], c));
#endif
}

// LLC-bypass (agent-scope relaxed) data ops: coherent across XCDs, no cache inv.
__device__ __forceinline__ unsigned ld_b32(const unsigned* p) {
  return __hip_atomic_load(p, __ATOMIC_RELAXED, __HIP_MEMORY_SCOPE_AGENT);
}
__device__ __forceinline__ void st_b32(unsigned* p, unsigned v) {
  __hip_atomic_store(p, v, __ATOMIC_RELAXED, __HIP_MEMORY_SCOPE_AGENT);
}
__device__ __forceinline__ unsigned long long ld_b64(const unsigned long long* p) {
  return __hip_atomic_load(p, __ATOMIC_RELAXED, __HIP_MEMORY_SCOPE_AGENT);
}
__device__ __forceinline__ void st_b64(unsigned long long* p, unsigned long long v) {
  __hip_atomic_store(p, v, __ATOMIC_RELAXED, __HIP_MEMORY_SCOPE_AGENT);
}
__device__ __forceinline__ void wait_flag(const int* p) {
  while (__hip_atomic_load(p, __ATOMIC_RELAXED, __HIP_MEMORY_SCOPE_AGENT) == 0)
    __builtin_amdgcn_s_sleep(1);
}
__device__ __forceinline__ void set_flag(int* p) {
  __hip_atomic_store(p, 1, __ATOMIC_RELAXED, __HIP_MEMORY_SCOPE_AGENT);
}

// ---------------- setup ----------------
__global__ __launch_bounds__(64) void setup_kernel(const int* __restrict__ caps, const int* __restrict__ caplens,
                                                   float* __restrict__ ws, float* __restrict__ out) {
  __shared__ int cl_s[64], so_s[64], dl_s[64], nb_s[49], ro_s[50];
  int i = threadIdx.x;
  cl_s[i] = caplens[i];
  __syncthreads();
  int cli = cl_s[i];
  int r = 0;
  for (int j = 0; j < 64; ++j) {
    int clj = cl_s[j];
    r += (clj > cli) || (clj == cli && j < i);   // stable descending
  }
  so_s[r] = i;
  dl_s[r] = cli - 1;
  __syncthreads();
  int* iws = (int*)ws;
  iws[WS_SORT + i] = so_s[i];
  iws[WS_DL + i] = dl_s[i];
  out[OUT_SORT + i] = (float)so_s[i];
  out[OUT_DL + i] = (float)dl_s[i];
  if (i < 49) {
    int n = 0;
    for (int b = 0; b < 64; ++b) n += (dl_s[b] > i);
    iws[WS_NB + i] = n;
    nb_s[i] = n;
  }
  __syncthreads();
  if (i == 0) {
    int acc = 0;
    for (int t = 0; t < 49; ++t) { ro_s[t] = acc; acc += nb_s[t]; }
    ro_s[49] = acc;
    iws[WS_NB + 49] = acc;
  }
  __syncthreads();
  if (i < 50) iws[WS_ROWOFF + i] = ro_s[i];
  int R = ro_s[49];
  for (int rr = i; rr < 3136; rr += 64) {
    int val = 0;
    if (rr < R) {
      int t = 0;
      while (t < 48 && ro_s[t + 1] <= rr) ++t;
      val = t * 64 + (rr - ro_s[t]);
    }
    iws[WS_RMAP + rr] = val;
    int b = rr / 49, tt = rr - b * 49;
    iws[WS_EROW + rr] = caps[so_s[b] * 50 + tt] * 512;
  }
  for (int j = i; j < 3200; j += 64) {
    int k = j / 50, jj = j - k * 50;
    int cv = caps[so_s[k] * 50 + jj];
    iws[WS_CAPS + j] = cv;
    out[OUT_CAPS + j] = (float)cv;
  }
}

// ---------------- zero: inactive out rows, c, xH, flags ----------------
__global__ __launch_bounds__(256) void zero_kernel(float* __restrict__ out, float* __restrict__ ws) {
  const int* iws = (const int*)ws;
  int r = blockIdx.x, tid = threadIdx.x;
  const float4 z = make_float4(0.f, 0.f, 0.f, 0.f);
  if (r < 3136) {
    int b = r / 49, t = r - b * 49;
    if (t >= iws[WS_DL + b]) {
      float4* sp = (float4*)out + (long)(b * 49 + t) * 2500;
      for (int i = tid; i < 2500; i += 256) sp[i] = z;
      if (tid < 49) ((float4*)(out + OUT_W))[(long)(b * 49 + t) * 49 + tid] = z;
    }
  } else {
    int b = r - 3136;
    if (tid < 128) ((float4*)(ws + WS_C))[b * 128 + tid] = z;
    else           ((float4*)(ws + WS_XH))[b * 128 + (tid - 128)] = z;
    int fl = b * 256 + tid;
    if (fl < 3936) ((int*)ws)[WS_CTXF + fl] = 0;     // CTXF(3136) + HF(800)
  }
}

// ---------------- W_dec -> WDT2 half2 [k-pair][a] (LDS transpose) ----------------
__global__ __launch_bounds__(256) void wdecT_kernel(const float* __restrict__ W, float* __restrict__ ws) {
  __shared__ float tl[64][65];
  int a0 = blockIdx.x * 64, k0 = blockIdx.y * 64;
  int tid = threadIdx.x;
#pragma unroll
  for (int it = 0; it < 4; ++it) {
    int lin = it * 256 + tid;
    int row = lin >> 4, c4 = lin & 15;
    float4 v = *(const float4*)(W + (long)(a0 + row) * 512 + k0 + c4 * 4);
    tl[row][c4 * 4 + 0] = v.x;
    tl[row][c4 * 4 + 1] = v.y;
    tl[row][c4 * 4 + 2] = v.z;
    tl[row][c4 * 4 + 3] = v.w;
  }
  __syncthreads();
  f16x2* dst = (f16x2*)(ws + WS_WDT);
#pragma unroll
  for (int it = 0; it < 8; ++it) {
    int lin = it * 256 + tid;
    int kk = lin >> 6, al = lin & 63;
    f16x2 h;
    h[0] = (_Float16)tl[al][2 * kk];
    h[1] = (_Float16)tl[al][2 * kk + 1];
    dst[((k0 >> 1) + kk) * 512 + a0 + al] = h;
  }
}

// ---------------- pack gates weights fp16, n' order; bias sums ----------------
__global__ __launch_bounds__(256) void wgh_kernel(const float* __restrict__ W_ih, const float* __restrict__ W_hh,
                                                  const float* __restrict__ b_ih, const float* __restrict__ b_hh,
                                                  float* __restrict__ ws) {
  int n = blockIdx.x;        // n' = d*4+g
  int g = n & 3, d = n >> 2, j = g * 512 + d;
  int tid = threadIdx.x;
  int k = tid * 4;
  float4 v = (k < 512) ? *(const float4*)(W_ih + (long)j * 1024 + 512 + k)
                       : *(const float4*)(W_hh + (long)j * 512 + (k - 512));
  f16x4 h;
  h[0] = (_Float16)v.x; h[1] = (_Float16)v.y; h[2] = (_Float16)v.z; h[3] = (_Float16)v.w;
  *(f16x4*)((_Float16*)(ws + WS_WGH) + (long)n * 1024 + k) = h;
  if (tid == 0) ws[WS_BS + n] = b_ih[j] + b_hh[j];
}

// ---------------- enc_att = feats_sorted @ W_enc^T + b_enc -> ENCH fp16 (MFMA) ----------------
__global__ __launch_bounds__(256) void encatt_kernel(const float* __restrict__ image, const float* __restrict__ W_enc,
                                                     const float* __restrict__ b_enc, float* __restrict__ ws) {
  __shared__ __align__(16) _Float16 ctile[128 * 136];
  __shared__ float benc_s[128];
  const int* iws = (const int*)ws;
  int mt = blockIdx.x, nt = blockIdx.y;   // (98, 4)
  int tid = threadIdx.x;
  int wv = tid >> 6, lane = tid & 63;
  int r16 = lane & 15, quad = lane >> 4;
  int m0 = mt * 128 + (wv & 1) * 64;
  int n0 = nt * 128 + (wv >> 1) * 64;
  if (tid < 128) benc_s[tid] = b_enc[nt * 128 + tid];
  long abase[4];
#pragma unroll
  for (int i = 0; i < 4; ++i) {
    int rm = m0 + i * 16 + r16;
    int b = rm / 196, p = rm - b * 196;
    abase[i] = ((long)iws[WS_SORT + b] * 196 + p) * 512;
  }
  floatx4 acc[4][4];
#pragma unroll
  for (int i = 0; i < 4; ++i)
#pragma unroll
    for (int j = 0; j < 4; ++j) acc[i][j] = (floatx4){0.f, 0.f, 0.f, 0.f};
#pragma unroll 2
  for (int kc = 0; kc < 16; ++kc) {
    int ko = kc * 32 + quad * 8;
    f16x8 a[4], bf[4];
#pragma unroll
    for (int i = 0; i < 4; ++i) {
      const float* p = image + abase[i] + ko;
      float4 v0 = *(const float4*)(p);
      float4 v1 = *(const float4*)(p + 4);
      a[i][0] = (_Float16)v0.x; a[i][1] = (_Float16)v0.y; a[i][2] = (_Float16)v0.z; a[i][3] = (_Float16)v0.w;
      a[i][4] = (_Float16)v1.x; a[i][5] = (_Float16)v1.y; a[i][6] = (_Float16)v1.z; a[i][7] = (_Float16)v1.w;
    }
#pragma unroll
    for (int j = 0; j < 4; ++j) {
      const float* p = W_enc + (long)(n0 + j * 16 + r16) * 512 + ko;
      float4 v0 = *(const float4*)(p);
      float4 v1 = *(const float4*)(p + 4);
      bf[j][0] = (_Float16)v0.x; bf[j][1] = (_Float16)v0.y; bf[j][2] = (_Float16)v0.z; bf[j][3] = (_Float16)v0.w;
      bf[j][4] = (_Float16)v1.x; bf[j][5] = (_Float16)v1.y; bf[j][6] = (_Float16)v1.z; bf[j][7] = (_Float16)v1.w;
    }
#pragma unroll
    for (int i = 0; i < 4; ++i)
#pragma unroll
      for (int j = 0; j < 4; ++j)
        acc[i][j] = __builtin_amdgcn_mfma_f32_16x16x32_f16(a[i], bf[j], acc[i][j], 0, 0, 0);
  }
  __syncthreads();
#pragma unroll
  for (int i = 0; i < 4; ++i) {
    int rl = (wv & 1) * 64 + i * 16 + quad * 4;
#pragma unroll
    for (int r = 0; r < 4; ++r)
#pragma unroll
      for (int j = 0; j < 4; ++j) {
        int cl = (wv >> 1) * 64 + j * 16 + r16;
        ctile[(rl + r) * 136 + cl] = (_Float16)(acc[i][j][r] + benc_s[cl]);
      }
  }
  __syncthreads();
  _Float16* encH = (_Float16*)(ws + WS_ENCH);
#pragma unroll
  for (int it = 0; it < 8; ++it) {
    int ch = it * 256 + tid;
    int row = ch >> 4, off = (ch & 15) * 8;
    f16x8 hv = *(f16x8*)(ctile + row * 136 + off);
    *(f16x8*)(encH + (long)(mt * 128 + row) * 512 + nt * 128 + off) = hv;
  }
}

// ---------------- G_emb = emb[caps_s] @ W_ih[:, :512]^T -> fp16, n' cols (MFMA) ----------------
__global__ __launch_bounds__(256) void embgates_kernel(float* __restrict__ ws, const float* __restrict__ emb,
                                                       const float* __restrict__ W_ih) {
  __shared__ __align__(16) _Float16 ctile[128 * 136];
  const int* iws = (const int*)ws;
  int mt = blockIdx.x, nt = blockIdx.y;   // (25, 16)
  int tid = threadIdx.x;
  int wv = tid >> 6, lane = tid & 63;
  int r16 = lane & 15, quad = lane >> 4;
  int m0 = mt * 128 + (wv & 1) * 64;
  int n0 = nt * 128 + (wv >> 1) * 64;
  long arow[4];
#pragma unroll
  for (int i = 0; i < 4; ++i) {
    int rm = m0 + i * 16 + r16;
    if (rm > 3135) rm = 3135;
    arow[i] = (long)iws[WS_EROW + rm];
  }
  floatx4 acc[4][4];
#pragma unroll
  for (int i = 0; i < 4; ++i)
#pragma unroll
    for (int j = 0; j < 4; ++j) acc[i][j] = (floatx4){0.f, 0.f, 0.f, 0.f};
#pragma unroll 2
  for (int kc = 0; kc < 16; ++kc) {
    int ko = kc * 32 + quad * 8;
    f16x8 a[4], bf[4];
#pragma unroll
    for (int i = 0; i < 4; ++i) {
      const float* p = emb + arow[i] + ko;
      float4 v0 = *(const float4*)(p);
      float4 v1 = *(const float4*)(p + 4);
      a[i][0] = (_Float16)v0.x; a[i][1] = (_Float16)v0.y; a[i][2] = (_Float16)v0.z; a[i][3] = (_Float16)v0.w;
      a[i][4] = (_Float16)v1.x; a[i][5] = (_Float16)v1.y; a[i][6] = (_Float16)v1.z; a[i][7] = (_Float16)v1.w;
    }
#pragma unroll
    for (int j = 0; j < 4; ++j) {
      int n = n0 + j * 16 + r16;                 // n'
      int rj = (n & 3) * 512 + (n >> 2);         // W_ih row
      const float* p = W_ih + (long)rj * 1024 + ko;
      float4 v0 = *(const float4*)(p);
      float4 v1 = *(const float4*)(p + 4);
      bf[j][0] = (_Float16)v0.x; bf[j][1] = (_Float16)v0.y; bf[j][2] = (_Float16)v0.z; bf[j][3] = (_Float16)v0.w;
      bf[j][4] = (_Float16)v1.x; bf[j][5] = (_Float16)v1.y; bf[j][6] = (_Float16)v1.z; bf[j][7] = (_Float16)v1.w;
    }
#pragma unroll
    for (int i = 0; i < 4; ++i)
#pragma unroll
      for (int j = 0; j < 4; ++j)
        acc[i][j] = __builtin_amdgcn_mfma_f32_16x16x32_f16(a[i], bf[j], acc[i][j], 0, 0, 0);
  }
  __syncthreads();
#pragma unroll
  for (int i = 0; i < 4; ++i) {
    int rl = (wv & 1) * 64 + i * 16 + quad * 4;
#pragma unroll
    for (int r = 0; r < 4; ++r)
#pragma unroll
      for (int j = 0; j < 4; ++j) {
        int cl = (wv >> 1) * 64 + j * 16 + r16;
        ctile[(rl + r) * 136 + cl] = (_Float16)acc[i][j][r];
      }
  }
  __syncthreads();
  _Float16* gembH = (_Float16*)(ws + WS_GEMB);
#pragma unroll
  for (int it = 0; it < 8; ++it) {
    int ch = it * 256 + tid;
    int row = ch >> 4, off = (ch & 15) * 8;
    int grow = mt * 128 + row;
    if (grow < 3136) {
      f16x8 hv = *(f16x8*)(ctile + row * 136 + off);
      *(f16x8*)(gembH + (long)grow * 2048 + nt * 128 + off) = hv;
    }
  }
}

// ---------------- persistent loop: blocks 0-63 attn, 64-79 gates+lstm; flag sync ----------------
#define GSTR 133
__global__ __launch_bounds__(512) void loop_kernel(float* __restrict__ ws, const float* __restrict__ image,
                                                   const float* __restrict__ W_full, const float* __restrict__ b_full,
                                                   const float* __restrict__ b_dec, float* __restrict__ out) {
  __shared__ __align__(16) float smem[64 * GSTR];
  int* iws = (int*)ws;
  int* ctxf = iws + WS_CTXF;
  int* hf = iws + WS_HF;
  unsigned* xHu = (unsigned*)(ws + WS_XH);
  _Float16* xHH = (_Float16*)(ws + WS_XH);
  const int bl = blockIdx.x;
  const int tid = threadIdx.x;
  const int wv = tid >> 6, lane = tid & 63;

  if (bl < 64) {
    // ================= attn role: b = bl =================
    const int b = bl;
    float* wf_s = smem;             // 512
    float* att2_s = smem + 512;     // 512
    float* e_s = smem + 1024;       // 200
    float* zred = smem + 1224;      // 8
    float* ctx_s = smem + 1232;     // 512
    unsigned* h2u = (unsigned*)(smem + 1744);  // 256
    wf_s[tid] = W_full[tid];
    const float bd = b_dec[tid];
    const float bf0 = b_full[0];
    const f16x2* wdt = (const f16x2*)(ws + WS_WDT);
    const _Float16* encH = (const _Float16*)(ws + WS_ENCH);
    const float* img = image + (long)iws[WS_SORT + b] * 100352;
    for (int t = 0; t < 49; ++t) {
      if (b >= iws[WS_NB + t]) return;
      if (t > 0) {
        if (tid < 16) wait_flag(&hf[(t - 1) * 16 + tid]);
      }
      __syncthreads();
      if (tid < 256) h2u[tid] = ld_b32(xHu + b * 512 + 256 + tid);   // h(t), LLC-fresh
      __syncthreads();
      // att2[a=tid] = h . W_dec[a] + b_dec[a]
      {
        float acc = 0.f;
#pragma unroll 8
        for (int kk = 0; kk < 256; ++kk) {
          union { unsigned u; f16x2 v; } cv; cv.u = h2u[kk];
          acc = dot2f(wdt[kk * 512 + tid], cv.v, acc);
        }
        att2_s[tid] = acc + bd;
      }
      __syncthreads();
      // e_p = W_full . relu(enc[p]+att2) + b_full ; e_s[p] = exp(e_p)
      {
        float at[8], wf[8];
#pragma unroll
        for (int q = 0; q < 8; ++q) { at[q] = att2_s[lane * 8 + q]; wf[q] = wf_s[lane * 8 + q]; }
        for (int i = 0; i < 25; ++i) {
          int p = wv + 8 * i;
          if (p < 196) {
            f16x8 ev = *(const f16x8*)(encH + (long)(b * 196 + p) * 512 + lane * 8);
            float acc = fmaxf((float)ev[0] + at[0], 0.f) * wf[0];
#pragma unroll
            for (int q = 1; q < 8; ++q) acc = fmaf(fmaxf((float)ev[q] + at[q], 0.f), wf[q], acc);
            acc = wave_reduce_sum(acc);
            if (lane == 0) e_s[p] = expf(acc + bf0);   // |e| small by construction
          }
        }
      }
      __syncthreads();
      float v = (tid < 196) ? e_s[tid] : 0.f;
      float sr = wave_reduce_sum(v);
      if (lane == 0) zred[wv] = sr;
      __syncthreads();
      float rz = 1.f / (zred[0] + zred[1] + zred[2] + zred[3] + zred[4] + zred[5] + zred[6] + zred[7]);
      if (tid < 196) out[OUT_W + (long)(b * 49 + t) * 196 + tid] = e_s[tid] * rz;
      // ctx[d=tid]
      {
        float acc = 0.f;
#pragma unroll 4
        for (int c = 0; c < 49; ++c) {
          float4 ev = *(const float4*)(e_s + c * 4);
          acc = fmaf(ev.x, img[(c * 4 + 0) * 512 + tid], acc);
          acc = fmaf(ev.y, img[(c * 4 + 1) * 512 + tid], acc);
          acc = fmaf(ev.z, img[(c * 4 + 2) * 512 + tid], acc);
          acc = fmaf(ev.w, img[(c * 4 + 3) * 512 + tid], acc);
        }
        ctx_s[tid] = acc * rz;
      }
      __syncthreads();
      if (tid < 256) {
        union { _Float16 h[2]; unsigned u; } pk;
        pk.h[0] = (_Float16)ctx_s[2 * tid];
        pk.h[1] = (_Float16)ctx_s[2 * tid + 1];
        st_b32(xHu + b * 512 + tid, pk.u);
      }
      __syncthreads();                 // drains vmcnt: ctx at LLC before flag
      if (tid == 0) set_flag(&ctxf[t * 64 + b]);
    }
  } else {
    // ================= gates+lstm role: g = bl-64, d range [g*32, g*32+32) =================
    const int g = bl - 64;
    const int r16 = lane & 15, quad = lane >> 4;
    const _Float16* WgH = (const _Float16*)(ws + WS_WGH);
    const _Float16* gemb0 = (const _Float16*)(ws + WS_GEMB);
    const int n0 = g * 128 + wv * 16;
    const int m = tid & 63, dgrp = tid >> 6;      // LSTM mapping
    const int d0 = g * 32 + dgrp * 4;
    const float* bs = ws + WS_BS + g * 128 + dgrp * 16;
    for (int t = 0; t < 49; ++t) {
      int nbt = iws[WS_NB + t];
      if (tid < 64 && tid < nbt) wait_flag(&ctxf[t * 64 + tid]);
      __syncthreads();
      floatx4 acc[4];
#pragma unroll
      for (int i = 0; i < 4; ++i) acc[i] = (floatx4){0.f, 0.f, 0.f, 0.f};
#pragma unroll 4
      for (int kc = 0; kc < 32; ++kc) {
        int ko = kc * 32 + quad * 8;
        f16x8 b8 = *(const f16x8*)(WgH + (long)(n0 + r16) * 1024 + ko);
#pragma unroll
        for (int i = 0; i < 4; ++i) {
          const unsigned long long* ap = (const unsigned long long*)(xHH + (size_t)(i * 16 + r16) * 1024 + ko);
          union { unsigned long long u[2]; f16x8 v; } cv;
          cv.u[0] = ld_b64(ap);
          cv.u[1] = ld_b64(ap + 1);
          acc[i] = __builtin_amdgcn_mfma_f32_16x16x32_f16(cv.v, b8, acc[i], 0, 0, 0);
        }
      }
#pragma unroll
      for (int i = 0; i < 4; ++i)
#pragma unroll
        for (int r = 0; r < 4; ++r)
          smem[(i * 16 + quad * 4 + r) * GSTR + wv * 16 + r16] = acc[i][r];
      __syncthreads();
      // LSTM for (m, d0..d0+3)
      {
        const _Float16* gp = gemb0 + ((long)(m * 49 + t)) * 2048 + g * 128 + dgrp * 16;
        f16x8 g0 = *(const f16x8*)(gp);
        f16x8 g1 = *(const f16x8*)(gp + 8);
        float4 cvld = *(const float4*)(ws + WS_C + m * 512 + d0);
        float cold[4] = {cvld.x, cvld.y, cvld.z, cvld.w};
        float cn4[4], hn4[4];
#pragma unroll
        for (int q = 0; q < 4; ++q) {
          float ge[4];
#pragma unroll
          for (int gg = 0; gg < 4; ++gg) {
            int nl = q * 4 + gg;
            float gv = (nl < 8) ? (float)g0[nl] : (float)g1[nl - 8];
            ge[gg] = smem[m * GSTR + dgrp * 16 + nl] + gv + bs[nl];
          }
          float cn = sigm(ge[1]) * cold[q] + sigm(ge[0]) * tanhf(ge[2]);
          float hn = sigm(ge[3]) * tanhf(cn);
          cn4[q] = cn; hn4[q] = hn;
        }
        if (m < nbt) {
          *(float4*)(ws + WS_C + m * 512 + d0) = make_float4(cn4[0], cn4[1], cn4[2], cn4[3]);
          f16x4 h4;
          h4[0] = (_Float16)hn4[0]; h4[1] = (_Float16)hn4[1]; h4[2] = (_Float16)hn4[2]; h4[3] = (_Float16)hn4[3];
          union { f16x4 v; unsigned long long u; } pk; pk.v = h4;
          st_b64((unsigned long long*)(xHH + (size_t)m * 1024 + 512 + d0), pk.u);
          *(f16x4*)((_Float16*)(ws + WS_HALLH) + (long)(iws[WS_ROWOFF + t] + m) * 512 + d0) = h4;
        }
      }
      __syncthreads();                 // drains vmcnt: h at LLC before flag; also Gs reuse safe
      if (tid == 0) set_flag(&hf[t * 16 + g]);
    }
  }
}

// ---------------- W_score fp32 -> fp16 (overlay) ----------------
__global__ void w2h_kernel(const float* __restrict__ W, float* __restrict__ ws) {
  _Float16* dst = (_Float16*)(ws + WS_WSH);
  int i = blockIdx.x * 256 + threadIdx.x;
  if (i < 1280000) {
    float4 v = ((const float4*)W)[i];
    f16x4 h;
    h[0] = (_Float16)v.x; h[1] = (_Float16)v.y; h[2] = (_Float16)v.z; h[3] = (_Float16)v.w;
    *(f16x4*)(dst + i * 4) = h;
  }
}

// ---------------- scores = HALL(fp16) @ W_score(fp16)^T + b_score (MFMA) ----------------
__global__ __launch_bounds__(256) void score_mfma_kernel(const float* __restrict__ ws,
                                                         const float* __restrict__ b_score,
                                                         float* __restrict__ out) {
  const int* iws = (const int*)ws;
  int R = iws[WS_NB + 49];
  int mt = blockIdx.x, nt = blockIdx.y;
  if (mt * 128 >= R) return;
  int tid = threadIdx.x;
  int wv = tid >> 6, lane = tid & 63;
  int m0 = mt * 128 + (wv & 1) * 64;
  int n0 = nt * 128 + (wv >> 1) * 64;
  int r16 = lane & 15, quad = lane >> 4;
  const _Float16* AH = (const _Float16*)(ws + WS_HALLH);
  const _Float16* BH = (const _Float16*)(ws + WS_WSH);
  floatx4 acc[4][4];
#pragma unroll
  for (int i = 0; i < 4; ++i)
#pragma unroll
    for (int j = 0; j < 4; ++j) acc[i][j] = (floatx4){0.f, 0.f, 0.f, 0.f};
#pragma unroll 4
  for (int kc = 0; kc < 16; ++kc) {
    int ko = kc * 32 + quad * 8;
    f16x8 a[4], b[4];
#pragma unroll
    for (int i = 0; i < 4; ++i) a[i] = *(const f16x8*)(AH + (long)(m0 + i * 16 + r16) * 512 + ko);
#pragma unroll
    for (int j = 0; j < 4; ++j) b[j] = *(const f16x8*)(BH + (long)(n0 + j * 16 + r16) * 512 + ko);
#pragma unroll
    for (int i = 0; i < 4; ++i)
#pragma unroll
      for (int j = 0; j < 4; ++j)
        acc[i][j] = __builtin_amdgcn_mfma_f32_16x16x32_f16(a[i], b[j], acc[i][j], 0, 0, 0);
  }
#pragma unroll
  for (int i = 0; i < 4; ++i) {
    int rbase = m0 + i * 16 + quad * 4;
#pragma unroll
    for (int r = 0; r < 4; ++r) {
      int grow = rbase + r;
      if (grow < R) {
        int tb = iws[WS_RMAP + grow];
        long obase = (long)(tb & 63) * 490000 + (long)(tb >> 6) * 10000;
#pragma unroll
        for (int j = 0; j < 4; ++j) {
          int col = n0 + j * 16 + r16;
          if (col < 10000) out[obase + col] = acc[i][j][r] + b_score[col];
        }
      }
    }
  }
}

// ---------------- launch ----------------
extern "C" void kernel_launch(void* const* d_in, const int* in_sizes, int n_in,
                              void* d_out, int out_size, void* d_ws, size_t ws_size,
                              hipStream_t stream) {
  const float* image   = (const float*)d_in[0];
  const int*   caps    = (const int*)d_in[1];
  const int*   caplens = (const int*)d_in[2];
  const float* emb     = (const float*)d_in[3];
  const float* W_ih    = (const float*)d_in[4];
  const float* W_hh    = (const float*)d_in[5];
  const float* b_ih    = (const float*)d_in[6];
  const float* b_hh    = (const float*)d_in[7];
  const float* W_enc   = (const float*)d_in[8];
  const float* b_enc   = (const float*)d_in[9];
  const float* W_dec   = (const float*)d_in[10];
  const float* b_dec   = (const float*)d_in[11];
  const float* W_full  = (const float*)d_in[12];
  const float* b_full  = (const float*)d_in[13];
  const float* W_score = (const float*)d_in[14];
  const float* b_score = (const float*)d_in[15];
  float* out = (float*)d_out;
  float* ws  = (float*)d_ws;

  setup_kernel<<<1, 64, 0, stream>>>(caps, caplens, ws, out);
  zero_kernel<<<3200, 256, 0, stream>>>(out, ws);
  wdecT_kernel<<<dim3(8, 8), 256, 0, stream>>>(W_dec, ws);
  wgh_kernel<<<2048, 256, 0, stream>>>(W_ih, W_hh, b_ih, b_hh, ws);
  encatt_kernel<<<dim3(98, 4), 256, 0, stream>>>(image, W_enc, b_enc, ws);
  embgates_kernel<<<dim3(25, 16), 256, 0, stream>>>(ws, emb, W_ih);
  loop_kernel<<<80, 512, 0, stream>>>(ws, image, W_full, b_full, b_dec, out);
  w2h_kernel<<<5000, 256, 0, stream>>>(W_score, ws);
  score_mfma_kernel<<<dim3(25, 79), 256, 0, stream>>>(ws, b_score, out);
}